// Round 16
// baseline (69.804 us; speedup 1.0000x reference)
//
#include <hip/hip_runtime.h>

// SigLoss: signature kernel PDE, loss = mean_a( K(X,X) + K(Y,Y) - 2 K(X,Y) ).
// A=256, L=256, D=32.
// R16 = R15's producer/consumer wave split with the barrier replaced by an
// LDS FLAG HANDSHAKE. R15's per-block __syncthreads drains vmcnt(0)+lgkmcnt(0)
// (global-load drain!) 16x/problem — overlap gain exactly cancelled (45us/WG
// = R14's serial time). Flags via __hip_atomic_* (workgroup scope) +
// __threadfence_block only wait lgkmcnt — cheap. Producer (MFMA inc blocks,
// ~900cyc) runs up to 2 blocks ahead of consumer (DPP scan, ~1300cyc);
// steady state = consumer-bound, no drains. Parity double-buffer: producer
// waits cons_done >= b-2 before overwriting.

typedef _Float16 half8 __attribute__((ext_vector_type(8)));
typedef float f32x4_t __attribute__((ext_vector_type(4)));
typedef unsigned int u32x4 __attribute__((ext_vector_type(4)));

#define DPP_ADD(v, ctrl, rmask)                                               \
    ((v) + __int_as_float(__builtin_amdgcn_update_dpp(                        \
               0, __float_as_int(v), (ctrl), (rmask), 0xF, true)))

#define INV2048 4.8828125e-4f

__global__ __launch_bounds__(128) void sig_pde(const float* __restrict__ X,
                                               const float* __restrict__ Y,
                                               float* __restrict__ partial) {
    const int bid = blockIdx.x;
    const int p = bid >> 8;          // 0=xx, 1=yy, 2=xy
    const int a = bid & 255;
    const float* __restrict__ U = (p == 1) ? Y : X;   // rows (i)
    const float* __restrict__ V = (p == 0) ? X : Y;   // cols (j)
    U += (size_t)a * 256 * 32;
    V += (size_t)a * 256 * 32;
    const int tid = threadIdx.x;
    const int wid = tid >> 6;            // 0 = producer, 1 = consumer
    const int lane = tid & 63;
    const int m16 = lane & 15;
    const int g2 = (lane >> 4) * 2;

    __shared__ __attribute__((aligned(16))) u32x4 bH[16 * 64];     // 16 KB
    __shared__ __attribute__((aligned(16))) u32x4 bL[16 * 64];     // 16 KB
    __shared__ __attribute__((aligned(16))) float incD[2][16 * 260]; // 33.3 KB
    __shared__ int prod_done_f;
    __shared__ int cons_done_f;

    const float4* U4 = (const float4*)U;
    const float4* V4 = (const float4*)V;

    if (tid == 0) { prod_done_f = -1; cons_done_f = -1; }

    // ---- Stage B fragments (split: wave w stages tiles w*8..w*8+7) ----
#pragma unroll 2
    for (int tt = 0; tt < 8; ++tt) {
        int t = wid * 8 + tt;
        int col = t * 16 + m16;
        int cp = (col + 1 < 256) ? col + 1 : 255;   // col 255 clamps -> dY=0
        float4 lo0 = V4[col * 8 + g2], lo1 = V4[col * 8 + g2 + 1];
        float4 hi0 = V4[cp * 8 + g2],  hi1 = V4[cp * 8 + g2 + 1];
        float d[8] = {hi0.x - lo0.x, hi0.y - lo0.y, hi0.z - lo0.z, hi0.w - lo0.w,
                      hi1.x - lo1.x, hi1.y - lo1.y, hi1.z - lo1.z, hi1.w - lo1.w};
        half8 bh, bl;
#pragma unroll
        for (int i = 0; i < 8; ++i) {
            _Float16 h = (_Float16)d[i];
            bh[i] = h;
            bl[i] = (_Float16)((d[i] - (float)h) * 2048.0f);
        }
        bH[t * 64 + lane] = __builtin_bit_cast(u32x4, bh);
        bL[t * 64 + lane] = __builtin_bit_cast(u32x4, bl);
    }
    __syncthreads();                     // once: B frags + flags visible

    if (wid == 0) {
        // ================= PRODUCER =================
        auto loadA = [&](int blk, float4 (&dst)[4]) {
            int r0 = blk * 16 + m16;
            int r1 = (r0 + 1 < 256) ? r0 + 1 : 255;   // dX[255]:=0 (unscanned)
            dst[0] = U4[r0 * 8 + g2];
            dst[1] = U4[r0 * 8 + g2 + 1];
            dst[2] = U4[r1 * 8 + g2];
            dst[3] = U4[r1 * 8 + g2 + 1];
        };
        const f32x4_t zero4 = {0.0f, 0.0f, 0.0f, 0.0f};
        const f32x4_t mone4 = {-1.0f, -1.0f, -1.0f, -1.0f};
        const int rb = (lane >> 4) << 2;   // C rows g*4..g*4+3

        float4 A[4];
        loadA(0, A);
#pragma clang loop unroll(disable)
        for (int b = 0; b < 16; ++b) {
            float d[8] = {A[2].x - A[0].x, A[2].y - A[0].y,
                          A[2].z - A[0].z, A[2].w - A[0].w,
                          A[3].x - A[1].x, A[3].y - A[1].y,
                          A[3].z - A[1].z, A[3].w - A[1].w};
            half8 ah, al;
#pragma unroll
            for (int i = 0; i < 8; ++i) {
                _Float16 h = (_Float16)d[i];
                ah[i] = h;
                al[i] = (_Float16)((d[i] - (float)h) * 2048.0f);
            }
            if (b + 1 < 16) loadA(b + 1, A);   // prefetch under MFMA phase
            // flow control: don't overwrite parity buffer until consumer done
            if (b >= 2) {
                while (__hip_atomic_load(&cons_done_f, __ATOMIC_RELAXED,
                                         __HIP_MEMORY_SCOPE_WORKGROUP) < b - 2)
                    __builtin_amdgcn_s_sleep(1);
            }
            float* __restrict__ inc = incD[b & 1];
#pragma unroll
            for (int t = 0; t < 16; ++t) {
                half8 bh = __builtin_bit_cast(half8, bH[t * 64 + lane]);
                half8 bl = __builtin_bit_cast(half8, bL[t * 64 + lane]);
                f32x4_t acc2 = __builtin_amdgcn_mfma_f32_16x16x32_f16(
                    ah, bl, zero4, 0, 0, 0);
                acc2 = __builtin_amdgcn_mfma_f32_16x16x32_f16(
                    al, bh, acc2, 0, 0, 0);
                f32x4_t acc1 = __builtin_amdgcn_mfma_f32_16x16x32_f16(
                    ah, bh, mone4, 0, 0, 0);
                int cc = t * 16 + m16;
                inc[(rb + 0) * 260 + cc] = fmaf(acc2[0], INV2048, acc1[0]);
                inc[(rb + 1) * 260 + cc] = fmaf(acc2[1], INV2048, acc1[1]);
                inc[(rb + 2) * 260 + cc] = fmaf(acc2[2], INV2048, acc1[2]);
                inc[(rb + 3) * 260 + cc] = fmaf(acc2[3], INV2048, acc1[3]);
            }
            __threadfence_block();         // drain ds_writes (lgkm only)
            if (lane == 0)
                __hip_atomic_store(&prod_done_f, b, __ATOMIC_RELAXED,
                                   __HIP_MEMORY_SCOPE_WORKGROUP);
        }
    } else {
        // ================= CONSUMER =================
        float kp0 = 1.0f, kp1 = 1.0f, kp2 = 1.0f, kp3 = 1.0f;

        auto scan_row = [&](float4 mv) {
            float kn = __int_as_float(__builtin_amdgcn_update_dpp(
                0, __float_as_int(kp0), 0x130 /*wave_shl:1*/, 0xF, 0xF, true));
            float c0 = fmaf(kp0, mv.x, kp1);
            float c1 = fmaf(kp1, mv.y, kp2);
            float c2 = fmaf(kp2, mv.z, kp3);
            float c3 = (lane == 63) ? 0.0f : fmaf(kp3, mv.w, kn);
            float L0 = c0, L1 = L0 + c1, L2 = L1 + c2;
            float T = L2 + c3;
            float S = T;
            S = DPP_ADD(S, 0x111, 0xF);  // row_shr:1
            S = DPP_ADD(S, 0x112, 0xF);  // row_shr:2
            S = DPP_ADD(S, 0x114, 0xF);  // row_shr:4
            S = DPP_ADD(S, 0x118, 0xF);  // row_shr:8
            S = DPP_ADD(S, 0x142, 0xA);  // row_bcast:15 -> rows 1,3
            S = DPP_ADD(S, 0x143, 0xC);  // row_bcast:31 -> rows 2,3
            float E = S - T;
            kp0 = 1.0f + E;
            kp1 = 1.0f + E + L0;
            kp2 = 1.0f + E + L1;
            kp3 = 1.0f + E + L2;
        };

#pragma clang loop unroll(disable)
        for (int b = 0; b < 16; ++b) {
            while (__hip_atomic_load(&prod_done_f, __ATOMIC_RELAXED,
                                     __HIP_MEMORY_SCOPE_WORKGROUP) < b)
                __builtin_amdgcn_s_sleep(1);
            __threadfence_block();         // acquire: order reads after flag
            const float4* rp = (const float4*)incD[b & 1];  // 65 f4 per row
            bool full = (b < 15);          // block 15: inc row 255 absent
            float4 ga0, ga1, ga2, ga3, gb0, gb1, gb2, gb3;
#define RD(Gv, r) Gv = rp[(r) * 65 + lane]
            RD(ga0, 0); RD(ga1, 1); RD(ga2, 2); RD(ga3, 3);
            RD(gb0, 4); RD(gb1, 5); RD(gb2, 6); RD(gb3, 7);
            scan_row(ga0); scan_row(ga1); scan_row(ga2); scan_row(ga3);
            RD(ga0, 8); RD(ga1, 9); RD(ga2, 10); RD(ga3, 11);
            scan_row(gb0); scan_row(gb1); scan_row(gb2); scan_row(gb3);
            RD(gb0, 12); RD(gb1, 13); RD(gb2, 14);
            if (full) RD(gb3, 15);
            scan_row(ga0); scan_row(ga1); scan_row(ga2); scan_row(ga3);
            scan_row(gb0); scan_row(gb1); scan_row(gb2);
            if (full) scan_row(gb3);
#undef RD
            __threadfence_block();         // reads done before publishing
            if (lane == 0)
                __hip_atomic_store(&cons_done_f, b, __ATOMIC_RELAXED,
                                   __HIP_MEMORY_SCOPE_WORKGROUP);
        }

        if (lane == 63) {
            // kp3 = K[255][255]
            partial[bid] = (p == 2 ? -2.0f : 1.0f) * kp3;
        }
    }
}

__global__ __launch_bounds__(256) void sig_reduce(const float* __restrict__ partial,
                                                  float* __restrict__ out) {
    const int t = threadIdx.x;
    float v = partial[t] + partial[t + 256] + partial[t + 512];
#pragma unroll
    for (int ofs = 32; ofs > 0; ofs >>= 1) v += __shfl_down(v, ofs);
    __shared__ float ws[4];
    if ((t & 63) == 0) ws[t >> 6] = v;
    __syncthreads();
    if (t == 0) out[0] = (ws[0] + ws[1] + ws[2] + ws[3]) * (1.0f / 256.0f);
}

extern "C" void kernel_launch(void* const* d_in, const int* in_sizes, int n_in,
                              void* d_out, int out_size, void* d_ws, size_t ws_size,
                              hipStream_t stream) {
    const float* X = (const float*)d_in[0];
    const float* Y = (const float*)d_in[1];
    float* partial = (float*)d_ws;       // 768 floats
    sig_pde<<<dim3(768), dim3(128), 0, stream>>>(X, Y, partial);
    sig_reduce<<<dim3(1), dim3(256), 0, stream>>>(partial, (float*)d_out);
}

// Round 17
// 56.598 us; speedup vs baseline: 1.2333x; 1.2333x over previous
//
#include <hip/hip_runtime.h>

// SigLoss: signature kernel PDE, loss = mean_a( K(X,X) + K(Y,Y) - 2 K(X,Y) ).
// A=256, L=256, D=32. One 64-lane wave per (pair,a) problem.
// R17 = R14 + sched_group_barrier-enforced per-row interleave. R14-R16 showed:
// per-wave VALU-busy ~37%, scan-chain stalls never filled despite adjacent
// independent MFMA work and no barriers -> the scheduler (pressure-driven)
// serializes the phases. SGB (compile-time scheduling directive) forces the
// per-row pattern: scan VALU / tile ds_reads / MFMA / DPP chain / ds_writes,
// dropping producer work into the chain's stall slots.

typedef _Float16 half8 __attribute__((ext_vector_type(8)));
typedef float f32x4_t __attribute__((ext_vector_type(4)));
typedef unsigned int u32x4 __attribute__((ext_vector_type(4)));

#define DPP_ADD(v, ctrl, rmask)                                               \
    ((v) + __int_as_float(__builtin_amdgcn_update_dpp(                        \
               0, __float_as_int(v), (ctrl), (rmask), 0xF, true)))

#define INV2048 4.8828125e-4f
#define SGB __builtin_amdgcn_sched_group_barrier

__global__ __launch_bounds__(64)
__attribute__((amdgpu_waves_per_eu(1, 1)))
void sig_pde(const float* __restrict__ X,
             const float* __restrict__ Y,
             float* __restrict__ partial) {
    const int bid = blockIdx.x;
    const int p = bid >> 8;          // 0=xx, 1=yy, 2=xy
    const int a = bid & 255;
    const float* __restrict__ U = (p == 1) ? Y : X;   // rows (i)
    const float* __restrict__ V = (p == 0) ? X : Y;   // cols (j)
    U += (size_t)a * 256 * 32;
    V += (size_t)a * 256 * 32;
    const int lane = threadIdx.x;
    const int m16 = lane & 15;           // row/col within MFMA tile
    const int g2 = (lane >> 4) * 2;      // k-group offset in float4 units

    __shared__ __attribute__((aligned(16))) u32x4 bH[16 * 64];   // 16 KB
    __shared__ __attribute__((aligned(16))) u32x4 bL[16 * 64];   // 16 KB
    __shared__ __attribute__((aligned(16))) float incL[16 * 260]; // 16.6 KB

    const float4* U4 = (const float4*)U;
    const float4* V4 = (const float4*)V;

    // ---- Stage B fragments: dY[n][k] hi/lo, frag layout n=lane&15,
    // k=(lane>>4)*8+i (B^T-GEMM idiom). Col 255 clamps -> dY=0. ----
#pragma unroll 2
    for (int t = 0; t < 16; ++t) {
        int col = t * 16 + m16;
        int cp = (col + 1 < 256) ? col + 1 : 255;
        float4 lo0 = V4[col * 8 + g2], lo1 = V4[col * 8 + g2 + 1];
        float4 hi0 = V4[cp * 8 + g2],  hi1 = V4[cp * 8 + g2 + 1];
        float d[8] = {hi0.x - lo0.x, hi0.y - lo0.y, hi0.z - lo0.z, hi0.w - lo0.w,
                      hi1.x - lo1.x, hi1.y - lo1.y, hi1.z - lo1.z, hi1.w - lo1.w};
        half8 bh, bl;
#pragma unroll
        for (int i = 0; i < 8; ++i) {
            _Float16 h = (_Float16)d[i];
            bh[i] = h;
            bl[i] = (_Float16)((d[i] - (float)h) * 2048.0f);
        }
        bH[t * 64 + lane] = __builtin_bit_cast(u32x4, bh);
        bL[t * 64 + lane] = __builtin_bit_cast(u32x4, bl);
    }
    // single wave: same-wave DS ordering, no barrier needed

    // K row state: kp{0..3} = K[r][4*lane+s], row 0 = ones
    float kp0 = 1.0f, kp1 = 1.0f, kp2 = 1.0f, kp3 = 1.0f;

    // A-frag raw rows: lane reads U[16b+m16][g*8..+8) and the next row.
    auto loadA = [&](int blk, float4 (&dst)[4]) {
        int r0 = blk * 16 + m16;
        int r1 = (r0 + 1 < 256) ? r0 + 1 : 255;   // dX[255] := 0 (unscanned)
        dst[0] = U4[r0 * 8 + g2];
        dst[1] = U4[r0 * 8 + g2 + 1];
        dst[2] = U4[r1 * 8 + g2];
        dst[3] = U4[r1 * 8 + g2 + 1];
    };

    // dX block -> two-term f16 split fragments
    auto makeAhAl = [&](const float4 (&src)[4], half8& ah, half8& al) {
        float d[8] = {src[2].x - src[0].x, src[2].y - src[0].y,
                      src[2].z - src[0].z, src[2].w - src[0].w,
                      src[3].x - src[1].x, src[3].y - src[1].y,
                      src[3].z - src[1].z, src[3].w - src[1].w};
#pragma unroll
        for (int i = 0; i < 8; ++i) {
            _Float16 h = (_Float16)d[i];
            ah[i] = h;
            al[i] = (_Float16)((d[i] - (float)h) * 2048.0f);
        }
    };

    // One scan row: mv = inc[r][4l..4l+3] - 1 (the -1 folded into MFMA)
    auto scan_row = [&](float4 mv) {
        float kn = __int_as_float(__builtin_amdgcn_update_dpp(
            0, __float_as_int(kp0), 0x130 /*wave_shl:1*/, 0xF, 0xF, true));
        float c0 = fmaf(kp0, mv.x, kp1);
        float c1 = fmaf(kp1, mv.y, kp2);
        float c2 = fmaf(kp2, mv.z, kp3);
        float c3 = (lane == 63) ? 0.0f : fmaf(kp3, mv.w, kn);
        float L0 = c0, L1 = L0 + c1, L2 = L1 + c2;
        float T = L2 + c3;
        float S = T;
        S = DPP_ADD(S, 0x111, 0xF);  // row_shr:1
        S = DPP_ADD(S, 0x112, 0xF);  // row_shr:2
        S = DPP_ADD(S, 0x114, 0xF);  // row_shr:4
        S = DPP_ADD(S, 0x118, 0xF);  // row_shr:8
        S = DPP_ADD(S, 0x142, 0xA);  // row_bcast:15 -> rows 1,3
        S = DPP_ADD(S, 0x143, 0xC);  // row_bcast:31 -> rows 2,3
        float E = S - T;
        kp0 = 1.0f + E;
        kp1 = 1.0f + E + L0;
        kp2 = 1.0f + E + L1;
        kp3 = 1.0f + E + L2;
    };

    const f32x4_t zero4 = {0.0f, 0.0f, 0.0f, 0.0f};
    const f32x4_t mone4 = {-1.0f, -1.0f, -1.0f, -1.0f};
    const int rb = (lane >> 4) << 2;     // C rows g*4..g*4+3

    // One MFMA col-tile: 3 mfma + combine + 4 inc writes
    auto mfma_tile = [&](int t, const half8& ah, const half8& al) {
        half8 bh = __builtin_bit_cast(half8, bH[t * 64 + lane]);
        half8 bl = __builtin_bit_cast(half8, bL[t * 64 + lane]);
        f32x4_t acc2 =
            __builtin_amdgcn_mfma_f32_16x16x32_f16(ah, bl, zero4, 0, 0, 0);
        acc2 = __builtin_amdgcn_mfma_f32_16x16x32_f16(al, bh, acc2, 0, 0, 0);
        f32x4_t acc1 =
            __builtin_amdgcn_mfma_f32_16x16x32_f16(ah, bh, mone4, 0, 0, 0);
        int cc = t * 16 + m16;
        incL[(rb + 0) * 260 + cc] = fmaf(acc2[0], INV2048, acc1[0]);
        incL[(rb + 1) * 260 + cc] = fmaf(acc2[1], INV2048, acc1[1]);
        incL[(rb + 2) * 260 + cc] = fmaf(acc2[2], INV2048, acc1[2]);
        incL[(rb + 3) * 260 + cc] = fmaf(acc2[3], INV2048, acc1[3]);
    };

    // Per-row enforced interleave: scan VALU / tile reads / MFMA / chain / wr
    auto sgb_row = [&]() {
        SGB(0x002, 4, 0);    // scan: kn + c0..c2
        SGB(0x100, 2, 0);    // tile: bH/bL ds_reads
        SGB(0x002, 6, 0);    // scan: c3, L's, T, first DPPs
        SGB(0x008, 3, 0);    // tile: 3 MFMAs
        SGB(0x002, 10, 0);   // scan: DPP chain tail + kp updates + combine
        SGB(0x200, 4, 0);    // tile: 4 inc ds_writes
    };

    const float4* rp = (const float4*)incL;   // 65 float4 per row

    // ---- Block 0 (no scan yet) ----
    float4 A[4];
    loadA(0, A);
    {
        half8 ah, al;
        makeAhAl(A, ah, al);
#pragma unroll
        for (int t = 0; t < 16; ++t) mfma_tile(t, ah, al);
    }

    // ---- Iterations b = 1..15: read16(b-1) | interleave scan/mfma(b) ----
#define RD(n) float4 w##n = rp[(n) * 65 + lane]
#pragma clang loop unroll(disable)
    for (int b = 1; b < 16; ++b) {
        loadA(b, A);                 // global loads; hidden under reads+scan
        // Issue ALL reads of block b-1 before any write of block b
        RD(0); RD(1); RD(2); RD(3); RD(4); RD(5); RD(6); RD(7);
        RD(8); RD(9); RD(10); RD(11); RD(12); RD(13); RD(14); RD(15);
        half8 ah, al;
        makeAhAl(A, ah, al);
        scan_row(w0);  mfma_tile(0, ah, al);  sgb_row();
        scan_row(w1);  mfma_tile(1, ah, al);  sgb_row();
        scan_row(w2);  mfma_tile(2, ah, al);  sgb_row();
        scan_row(w3);  mfma_tile(3, ah, al);  sgb_row();
        scan_row(w4);  mfma_tile(4, ah, al);  sgb_row();
        scan_row(w5);  mfma_tile(5, ah, al);  sgb_row();
        scan_row(w6);  mfma_tile(6, ah, al);  sgb_row();
        scan_row(w7);  mfma_tile(7, ah, al);  sgb_row();
        scan_row(w8);  mfma_tile(8, ah, al);  sgb_row();
        scan_row(w9);  mfma_tile(9, ah, al);  sgb_row();
        scan_row(w10); mfma_tile(10, ah, al); sgb_row();
        scan_row(w11); mfma_tile(11, ah, al); sgb_row();
        scan_row(w12); mfma_tile(12, ah, al); sgb_row();
        scan_row(w13); mfma_tile(13, ah, al); sgb_row();
        scan_row(w14); mfma_tile(14, ah, al); sgb_row();
        scan_row(w15); mfma_tile(15, ah, al); sgb_row();
    }

    // ---- Tail: scan block 15 (15 rows; inc row 255 doesn't exist) ----
    {
        RD(0); RD(1); RD(2); RD(3); RD(4); RD(5); RD(6); RD(7);
        RD(8); RD(9); RD(10); RD(11); RD(12); RD(13); RD(14);
        scan_row(w0); scan_row(w1); scan_row(w2); scan_row(w3);
        scan_row(w4); scan_row(w5); scan_row(w6); scan_row(w7);
        scan_row(w8); scan_row(w9); scan_row(w10); scan_row(w11);
        scan_row(w12); scan_row(w13); scan_row(w14);
    }
#undef RD

    if (lane == 63) {
        // kp3 = K[255][255]
        partial[bid] = (p == 2 ? -2.0f : 1.0f) * kp3;
    }
}

__global__ __launch_bounds__(256) void sig_reduce(const float* __restrict__ partial,
                                                  float* __restrict__ out) {
    const int t = threadIdx.x;
    float v = partial[t] + partial[t + 256] + partial[t + 512];
#pragma unroll
    for (int ofs = 32; ofs > 0; ofs >>= 1) v += __shfl_down(v, ofs);
    __shared__ float ws[4];
    if ((t & 63) == 0) ws[t >> 6] = v;
    __syncthreads();
    if (t == 0) out[0] = (ws[0] + ws[1] + ws[2] + ws[3]) * (1.0f / 256.0f);
}

extern "C" void kernel_launch(void* const* d_in, const int* in_sizes, int n_in,
                              void* d_out, int out_size, void* d_ws, size_t ws_size,
                              hipStream_t stream) {
    const float* X = (const float*)d_in[0];
    const float* Y = (const float*)d_in[1];
    float* partial = (float*)d_ws;       // 768 floats
    sig_pde<<<dim3(768), dim3(64), 0, stream>>>(X, Y, partial);
    sig_reduce<<<dim3(1), dim3(256), 0, stream>>>(partial, (float*)d_out);
}

// Round 18
// 45.279 us; speedup vs baseline: 1.5417x; 1.2500x over previous
//
#include <hip/hip_runtime.h>

// SigLoss: signature kernel PDE, loss = mean_a( K(X,X) + K(Y,Y) - 2 K(X,Y) ).
// A=256, L=256, D=32. One 64-lane wave per (pair,a) problem.
// R18 = R13 with B FRAGMENTS IN REGISTERS. Budget audit of R13/R14's 105k cyc
// (issue ~29k, scan chain ~20k, MFMA ~6k) pins the missing ~50k on per-tile
// LDS waits: each mfma_tile did 2 ds_read(bH/bL) -> lgkmcnt wait -> mfma ->
// 4 ds_write, ~120+cyc exposed x256 tiles. Each lane only needs ITS OWN frag
// per tile: bh[16]+bl[16] half8 = 128 VGPR, loaded once from global, no LDS.
// MFMA phase becomes register-only except inc writes. incD double-buffered
// (33.3 KB) so scan(b-1) reads never order against mfma(b) writes. VGPR
// demand ~190 ~= the 192 grant R13 proved (waves_per_eu(1,1)).

typedef _Float16 half8 __attribute__((ext_vector_type(8)));
typedef float f32x4_t __attribute__((ext_vector_type(4)));

#define DPP_ADD(v, ctrl, rmask)                                               \
    ((v) + __int_as_float(__builtin_amdgcn_update_dpp(                        \
               0, __float_as_int(v), (ctrl), (rmask), 0xF, true)))

#define INV2048 4.8828125e-4f

__global__ __launch_bounds__(64)
__attribute__((amdgpu_waves_per_eu(1, 1)))
void sig_pde(const float* __restrict__ X,
             const float* __restrict__ Y,
             float* __restrict__ partial) {
    const int bid = blockIdx.x;
    const int p = bid >> 8;          // 0=xx, 1=yy, 2=xy
    const int a = bid & 255;
    const float* __restrict__ U = (p == 1) ? Y : X;   // rows (i)
    const float* __restrict__ V = (p == 0) ? X : Y;   // cols (j)
    U += (size_t)a * 256 * 32;
    V += (size_t)a * 256 * 32;
    const int lane = threadIdx.x;
    const int m16 = lane & 15;           // row/col within MFMA tile
    const int g2 = (lane >> 4) * 2;      // k-group offset in float4 units

    __shared__ __attribute__((aligned(16))) float incD[2][16 * 260]; // 33.3 KB

    const float4* U4 = (const float4*)U;
    const float4* V4 = (const float4*)V;

    // ---- B fragments dY[n][k] hi/lo in REGISTERS: lane's frag for tile t is
    // col t*16+(lane&15), k = (lane>>4)*8..+8 (B^T-GEMM idiom). 128 VGPR. ----
    half8 bh[16], bl[16];
#pragma unroll
    for (int t = 0; t < 16; ++t) {
        int col = t * 16 + m16;
        int cp = (col + 1 < 256) ? col + 1 : 255;   // col 255 clamps -> dY=0
        float4 lo0 = V4[col * 8 + g2], lo1 = V4[col * 8 + g2 + 1];
        float4 hi0 = V4[cp * 8 + g2],  hi1 = V4[cp * 8 + g2 + 1];
        float d[8] = {hi0.x - lo0.x, hi0.y - lo0.y, hi0.z - lo0.z, hi0.w - lo0.w,
                      hi1.x - lo1.x, hi1.y - lo1.y, hi1.z - lo1.z, hi1.w - lo1.w};
#pragma unroll
        for (int i = 0; i < 8; ++i) {
            _Float16 h = (_Float16)d[i];
            bh[t][i] = h;
            bl[t][i] = (_Float16)((d[i] - (float)h) * 2048.0f);
        }
    }

    // K row state: kp{0..3} = K[r][4*lane+s], row 0 = ones
    float kp0 = 1.0f, kp1 = 1.0f, kp2 = 1.0f, kp3 = 1.0f;

    // A-frag raw rows: lane reads U[16b+m16][g*8..+8) and the next row.
    auto loadA = [&](int blk, float4 (&dst)[4]) {
        int r0 = blk * 16 + m16;
        int r1 = (r0 + 1 < 256) ? r0 + 1 : 255;   // dX[255] := 0 (unscanned)
        dst[0] = U4[r0 * 8 + g2];
        dst[1] = U4[r0 * 8 + g2 + 1];
        dst[2] = U4[r1 * 8 + g2];
        dst[3] = U4[r1 * 8 + g2 + 1];
    };

    // One scan row: mv = inc[r][4l..4l+3] - 1 (the -1 folded into MFMA)
    auto scan_row = [&](float4 mv) {
        float kn = __int_as_float(__builtin_amdgcn_update_dpp(
            0, __float_as_int(kp0), 0x130 /*wave_shl:1*/, 0xF, 0xF, true));
        float c0 = fmaf(kp0, mv.x, kp1);
        float c1 = fmaf(kp1, mv.y, kp2);
        float c2 = fmaf(kp2, mv.z, kp3);
        float c3 = (lane == 63) ? 0.0f : fmaf(kp3, mv.w, kn);
        float L0 = c0, L1 = L0 + c1, L2 = L1 + c2;
        float T = L2 + c3;
        float S = T;
        S = DPP_ADD(S, 0x111, 0xF);  // row_shr:1
        S = DPP_ADD(S, 0x112, 0xF);  // row_shr:2
        S = DPP_ADD(S, 0x114, 0xF);  // row_shr:4
        S = DPP_ADD(S, 0x118, 0xF);  // row_shr:8
        S = DPP_ADD(S, 0x142, 0xA);  // row_bcast:15 -> rows 1,3
        S = DPP_ADD(S, 0x143, 0xC);  // row_bcast:31 -> rows 2,3
        float E = S - T;
        kp0 = 1.0f + E;
        kp1 = 1.0f + E + L0;
        kp2 = 1.0f + E + L1;
        kp3 = 1.0f + E + L2;
    };

    // Unrolled 16-row scan from buf: 4-row groups, double-buffered prefetch.
#define RD(Gv, r) Gv = rp[(r) * 65 + lane]
    auto scan16 = [&](const float* buf, bool full) {
        const float4* rp = (const float4*)buf;    // 65 float4 per row
        float4 ga0, ga1, ga2, ga3, gb0, gb1, gb2, gb3;
        RD(ga0, 0); RD(ga1, 1); RD(ga2, 2); RD(ga3, 3);
        RD(gb0, 4); RD(gb1, 5); RD(gb2, 6); RD(gb3, 7);
        scan_row(ga0); scan_row(ga1); scan_row(ga2); scan_row(ga3);
        RD(ga0, 8); RD(ga1, 9); RD(ga2, 10); RD(ga3, 11);
        scan_row(gb0); scan_row(gb1); scan_row(gb2); scan_row(gb3);
        RD(gb0, 12); RD(gb1, 13); RD(gb2, 14);
        if (full) RD(gb3, 15);
        scan_row(ga0); scan_row(ga1); scan_row(ga2); scan_row(ga3);
        scan_row(gb0); scan_row(gb1); scan_row(gb2);
        if (full) scan_row(gb3);
    };
#undef RD

    // MFMA one 16-row block into buf: 16 reg-only col-tiles + inc writes.
    auto mfma_block = [&](const float4 (&src)[4], float* __restrict__ buf) {
        float d[8] = {src[2].x - src[0].x, src[2].y - src[0].y,
                      src[2].z - src[0].z, src[2].w - src[0].w,
                      src[3].x - src[1].x, src[3].y - src[1].y,
                      src[3].z - src[1].z, src[3].w - src[1].w};
        half8 ah, al;
#pragma unroll
        for (int i = 0; i < 8; ++i) {
            _Float16 h = (_Float16)d[i];
            ah[i] = h;
            al[i] = (_Float16)((d[i] - (float)h) * 2048.0f);
        }
        const f32x4_t zero4 = {0.0f, 0.0f, 0.0f, 0.0f};
        const f32x4_t mone4 = {-1.0f, -1.0f, -1.0f, -1.0f};
        const int rb = (lane >> 4) << 2;   // C rows g*4..g*4+3
#pragma unroll
        for (int t = 0; t < 16; ++t) {
            f32x4_t acc2 =
                __builtin_amdgcn_mfma_f32_16x16x32_f16(ah, bl[t], zero4, 0, 0, 0);
            acc2 = __builtin_amdgcn_mfma_f32_16x16x32_f16(al, bh[t], acc2, 0, 0, 0);
            f32x4_t acc1 =
                __builtin_amdgcn_mfma_f32_16x16x32_f16(ah, bh[t], mone4, 0, 0, 0);
            int cc = t * 16 + m16;
            buf[(rb + 0) * 260 + cc] = fmaf(acc2[0], INV2048, acc1[0]);
            buf[(rb + 1) * 260 + cc] = fmaf(acc2[1], INV2048, acc1[1]);
            buf[(rb + 2) * 260 + cc] = fmaf(acc2[2], INV2048, acc1[2]);
            buf[(rb + 3) * 260 + cc] = fmaf(acc2[3], INV2048, acc1[3]);
        }
    };

    // Main pipeline: mfma(0); for b=1..15 { loadA(b) | scan(b-1) | mfma(b) }
    float4 A[4];
    loadA(0, A);
    mfma_block(A, incD[0]);
#pragma clang loop unroll(disable)
    for (int b = 1; b < 16; ++b) {
        loadA(b, A);                     // global loads; hidden under scan
        scan16(incD[(b - 1) & 1], true); // scan block b-1
        mfma_block(A, incD[b & 1]);      // reg-only MFMA + writes
    }
    scan16(incD[1], false);              // block 15: 15 rows (row 255 n/a)

    if (lane == 63) {
        // kp3 = K[255][255]
        partial[bid] = (p == 2 ? -2.0f : 1.0f) * kp3;
    }
}

__global__ __launch_bounds__(256) void sig_reduce(const float* __restrict__ partial,
                                                  float* __restrict__ out) {
    const int t = threadIdx.x;
    float v = partial[t] + partial[t + 256] + partial[t + 512];
#pragma unroll
    for (int ofs = 32; ofs > 0; ofs >>= 1) v += __shfl_down(v, ofs);
    __shared__ float ws[4];
    if ((t & 63) == 0) ws[t >> 6] = v;
    __syncthreads();
    if (t == 0) out[0] = (ws[0] + ws[1] + ws[2] + ws[3]) * (1.0f / 256.0f);
}

extern "C" void kernel_launch(void* const* d_in, const int* in_sizes, int n_in,
                              void* d_out, int out_size, void* d_ws, size_t ws_size,
                              hipStream_t stream) {
    const float* X = (const float*)d_in[0];
    const float* Y = (const float*)d_in[1];
    float* partial = (float*)d_ws;       // 768 floats
    sig_pde<<<dim3(768), dim3(64), 0, stream>>>(X, Y, partial);
    sig_reduce<<<dim3(1), dim3(256), 0, stream>>>(partial, (float*)d_out);
}